// Round 8
// baseline (280.328 us; speedup 1.0000x reference)
//
#include <hip/hip_runtime.h>
#include <hip/hip_bf16.h>
#include <math.h>

#define H 1024
#define R 64
#define NTHREADS 256
#define TSTRIDE 72   // t buffer row stride (shorts): 144B, benign banks

typedef __attribute__((ext_vector_type(8))) short short8;
typedef __attribute__((ext_vector_type(4))) float floatx4;

#define GLD_LDS(gp, lp) \
    __builtin_amdgcn_global_load_lds((const __attribute__((address_space(1))) void*)(gp), \
                                     (__attribute__((address_space(3))) void*)(lp), 16, 0, 0)

__device__ __forceinline__ unsigned short f2bf(float f) {
    unsigned int u = __builtin_bit_cast(unsigned int, f);
    u += 0x7fffu + ((u >> 16) & 1u);   // round-to-nearest-even
    return (unsigned short)(u >> 16);
}

// ---- single prep kernel: blocks 0..255 pack weight frags; 256..319 colsums ----
// frag f, lane l, elem j -> ws[(f*64+l)*8+j]; k = (l>>4)*8 + j within k-tile
__global__ void prep(const float* __restrict__ w_down,
                     const float* __restrict__ w_up,
                     const float* __restrict__ gamma,
                     const float* __restrict__ beta,
                     const float* __restrict__ b_down,
                     unsigned short* __restrict__ wsd,
                     unsigned short* __restrict__ wsu,
                     float* __restrict__ w1, float* __restrict__ c0) {
    __shared__ float red[8];
    int bid = blockIdx.x;
    if (bid < 256) {
        int tid = bid * NTHREADS + threadIdx.x;        // 0..65535
        int j    = tid & 7;
        int lane = (tid >> 3) & 63;
        int f    = tid >> 9;                           // 0..127
        int b = lane >> 4, p = lane & 15;
        {   // W' = gamma * W_down: f = kk*4 + n
            int kk = f >> 2, n = f & 3;
            int row = kk * 32 + b * 8 + j;
            int col = n * 16 + p;
            wsd[tid] = f2bf(gamma[row] * w_down[row * R + col]);
        }
        {   // W_up: f = ks*64 + n
            int ks = f >> 6, n = f & 63;
            int row = ks * 32 + b * 8 + j;
            int col = n * 16 + p;
            wsu[tid] = f2bf(w_up[row * H + col]);
        }
    } else {
        int r = bid - 256;                 // 0..63
        int t = threadIdx.x;
        float a = 0.f, c = 0.f;
        for (int h = t; h < H; h += NTHREADS) {
            float wd = w_down[h * R + r];
            a += gamma[h] * wd;
            c += beta[h] * wd;
        }
        #pragma unroll
        for (int off = 32; off >= 1; off >>= 1) {
            a += __shfl_xor(a, off);
            c += __shfl_xor(c, off);
        }
        int wv = t >> 6;
        if ((t & 63) == 0) { red[wv] = a; red[4 + wv] = c; }
        __syncthreads();
        if (t == 0) {
            w1[r] = red[0] + red[1] + red[2] + red[3];
            c0[r] = red[4] + red[5] + red[6] + red[7] + b_down[r];
        }
    }
}

// Wave-local 16 rows end-to-end. Weights staged to LDS (ds_read/lgkmcnt),
// decoupled from the x/residual/store vmcnt stream to avoid ordered-vmcnt
// entanglement of fast (L2) and slow (HBM) loads. Double-buffered 16 KB
// chunks, one __syncthreads per chunk.
__global__ __launch_bounds__(NTHREADS, 2)
void adapter_kernel(const float* __restrict__ x,
                    const float* __restrict__ b_up,
                    const unsigned short* __restrict__ wsd,
                    const unsigned short* __restrict__ wsu,
                    const float* __restrict__ w1v,
                    const float* __restrict__ c0v,
                    float* __restrict__ out) {
    __shared__ __align__(16) unsigned short wbuf[2][8192];          // 32 KB
    __shared__ __align__(16) unsigned short t_lds[4][16 * TSTRIDE]; // 9.2 KB

    const int tid  = threadIdx.x;
    const int lane = tid & 63;
    const int w    = tid >> 6;
    const int p    = lane & 15;
    const int b    = lane >> 4;
    const long row0 = (long)blockIdx.x * 64 + w * 16;
    const float* xw = x + (row0 + p) * H + b * 8;

    float s1 = 0.f, s2 = 0.f;
    floatx4 acc[4];
    #pragma unroll
    for (int nt = 0; nt < 4; ++nt) acc[nt] = floatx4{0.f, 0.f, 0.f, 0.f};

    // ====================== down-proj: 8 chunks of 4 k-steps ================
    // stage: chunk c = frags c*16 .. c*16+15 (16 KB); wave stages 4 frags
    auto stage_d = [&](int c, int buf) {
        #pragma unroll
        for (int i = 0; i < 4; ++i) {
            int fl = w * 4 + i;                       // frag-local 0..15
            GLD_LDS(wsd + ((size_t)(c * 16 + fl) * 64 + lane) * 8,
                    &wbuf[buf][fl * 512]);
        }
    };
    auto loadx = [&](int c, floatx4* v0, floatx4* v1) {
        #pragma unroll
        for (int i = 0; i < 4; ++i) {
            v0[i] = *(const floatx4*)(xw + (c * 4 + i) * 32);
            v1[i] = *(const floatx4*)(xw + (c * 4 + i) * 32 + 4);
        }
    };
    auto compute_d = [&](const floatx4* v0, const floatx4* v1,
                         const unsigned short* wb) {
        #pragma unroll
        for (int i = 0; i < 4; ++i) {
            short8 a;
            #pragma unroll
            for (int e = 0; e < 4; ++e) {
                float f0 = v0[i][e], f1 = v1[i][e];
                s1 += f0 + f1;
                s2 += f0 * f0 + f1 * f1;
                a[e]     = (short)f2bf(f0);
                a[4 + e] = (short)f2bf(f1);
            }
            #pragma unroll
            for (int nt = 0; nt < 4; ++nt)
                acc[nt] = __builtin_amdgcn_mfma_f32_16x16x32_bf16(
                    a, *(const short8*)&wb[(i * 4 + nt) * 512 + lane * 8],
                    acc[nt], 0, 0, 0);
        }
    };

    floatx4 xA0[4], xA1[4], xB0[4], xB1[4];
    stage_d(0, 0);
    loadx(0, xA0, xA1);
    __syncthreads();                       // stage(0)+x(0) complete & visible
    #pragma unroll
    for (int c = 0; c < 8; ++c) {
        if (c + 1 < 8) {
            if (((c + 1) & 1) == 1) { stage_d(c + 1, 1); loadx(c + 1, xB0, xB1); }
            else                    { stage_d(c + 1, 0); loadx(c + 1, xA0, xA1); }
        }
        if ((c & 1) == 0) compute_d(xA0, xA1, wbuf[0]);
        else              compute_d(xB0, xB1, wbuf[1]);
        __syncthreads();                   // drain stage(c+1)/x(c+1); buf swap safe
    }

    // ---- row stats (reduce over b), folded LN + GELU, t -> wave LDS --------
    s1 += __shfl_xor(s1, 16); s1 += __shfl_xor(s1, 32);
    s2 += __shfl_xor(s2, 16); s2 += __shfl_xor(s2, 32);
    float mu = s1 * (1.0f / (float)H);
    float var = s2 * (1.0f / (float)H) - mu * mu;
    float rs = rsqrtf(var + 1e-5f);

    #pragma unroll
    for (int reg = 0; reg < 4; ++reg) {
        float mur = __shfl(mu, b * 4 + reg);
        float rsr = __shfl(rs, b * 4 + reg);
        #pragma unroll
        for (int nt = 0; nt < 4; ++nt) {
            int col = nt * 16 + p;
            float u = rsr * (acc[nt][reg] - mur * w1v[col]) + c0v[col];
            u = 0.5f * u * (1.0f + erff(u * 0.70710678f));
            t_lds[w][(b * 4 + reg) * TSTRIDE + col] = f2bf(u);
        }
    }

    // ====================== up-proj: 8 chunks of 8 n-tiles ==================
    const long rbase = row0 + b * 4;
    auto stage_u = [&](int c, int buf) {
        #pragma unroll
        for (int i = 0; i < 2; ++i) {
            int nl = w * 2 + i;                       // n-local 0..7
            GLD_LDS(wsu + ((size_t)(c * 8 + nl) * 64 + lane) * 8,
                    &wbuf[buf][nl * 512]);
            GLD_LDS(wsu + ((size_t)(64 + c * 8 + nl) * 64 + lane) * 8,
                    &wbuf[buf][4096 + nl * 512]);
        }
    };

    stage_u(0, 0);                          // buf0 free (last read chunk 6)
    float rx0[8], rx1[8], rx2[8], rx3[8], bb[8];   // 8-deep residual/bias roll
    #pragma unroll
    for (int i = 0; i < 8; ++i) {
        int col = i * 16 + p;
        bb[i]  = b_up[col];
        rx0[i] = x[(rbase + 0) * H + col];
        rx1[i] = x[(rbase + 1) * H + col];
        rx2[i] = x[(rbase + 2) * H + col];
        rx3[i] = x[(rbase + 3) * H + col];
    }
    __syncthreads();                        // t_lds visible + stage_u(0) landed
    short8 a0 = *(const short8*)&t_lds[w][p * TSTRIDE + b * 8];        // k 0..31
    short8 a1 = *(const short8*)&t_lds[w][p * TSTRIDE + 32 + b * 8];   // k 32..63

    auto up_chunk = [&](int c, const unsigned short* wb) {
        #pragma unroll
        for (int ni = 0; ni < 8; ++ni) {
            const int n = c * 8 + ni;
            short8 bu0 = *(const short8*)&wb[ni * 512 + lane * 8];
            short8 bu1 = *(const short8*)&wb[4096 + ni * 512 + lane * 8];
            floatx4 av = {0.f, 0.f, 0.f, 0.f};
            av = __builtin_amdgcn_mfma_f32_16x16x32_bf16(a0, bu0, av, 0, 0, 0);
            av = __builtin_amdgcn_mfma_f32_16x16x32_bf16(a1, bu1, av, 0, 0, 0);
            const int col = n * 16 + p;
            float bup = bb[ni], r0 = rx0[ni], r1 = rx1[ni], r2 = rx2[ni], r3 = rx3[ni];
            if (n + 8 < 64) {               // refill slot ni for chunk c+1
                const int colc = (n + 8) * 16 + p;
                bb[ni]  = b_up[colc];
                rx0[ni] = x[(rbase + 0) * H + colc];
                rx1[ni] = x[(rbase + 1) * H + colc];
                rx2[ni] = x[(rbase + 2) * H + colc];
                rx3[ni] = x[(rbase + 3) * H + colc];
            }
            out[(rbase + 0) * H + col] = av[0] + bup + r0;
            out[(rbase + 1) * H + col] = av[1] + bup + r1;
            out[(rbase + 2) * H + col] = av[2] + bup + r2;
            out[(rbase + 3) * H + col] = av[3] + bup + r3;
        }
    };

    #pragma unroll
    for (int c = 0; c < 8; ++c) {
        if (c + 1 < 8) stage_u(c + 1, (c + 1) & 1);
        if ((c & 1) == 0) up_chunk(c, wbuf[0]);
        else              up_chunk(c, wbuf[1]);
        if (c + 1 < 8) __syncthreads();
    }
}

extern "C" void kernel_launch(void* const* d_in, const int* in_sizes, int n_in,
                              void* d_out, int out_size, void* d_ws, size_t ws_size,
                              hipStream_t stream) {
    const float* x      = (const float*)d_in[0];
    const float* gamma  = (const float*)d_in[1];
    const float* beta   = (const float*)d_in[2];
    const float* w_down = (const float*)d_in[3];
    const float* b_down = (const float*)d_in[4];
    const float* w_up   = (const float*)d_in[5];
    const float* b_up   = (const float*)d_in[6];
    float* out = (float*)d_out;

    unsigned short* wsd = (unsigned short*)d_ws;
    unsigned short* wsu = wsd + 65536;
    float* w1 = (float*)(wsu + 65536);
    float* c0 = w1 + 64;

    int M = in_sizes[0] / H;                 // 32768 rows
    prep<<<320, NTHREADS, 0, stream>>>(w_down, w_up, gamma, beta, b_down,
                                       wsd, wsu, w1, c0);
    adapter_kernel<<<M / 64, NTHREADS, 0, stream>>>(x, b_up, wsd, wsu, w1, c0, out);
}